// Round 23
// baseline (55.683 us; speedup 1.0000x reference)
//
#include <hip/hip_runtime.h>

#define BB 32
#define NN 1024
#define MM 1024
#define DD 128

typedef __attribute__((ext_vector_type(4))) float f32x4;
typedef __attribute__((ext_vector_type(8))) __bf16 bf16x8;
typedef unsigned short ushort_t;
typedef unsigned int uint_t;

#define L2E 1.44269504f

__device__ __forceinline__ unsigned f2bf(float x) {
    unsigned u = __builtin_bit_cast(unsigned, x);
    return (u + 0x7fffu + ((u >> 16) & 1u)) >> 16;  // RNE bf16, finite inputs
}

// async global->LDS, 16 B per lane; dest must be linear (base + lane*16)
#define GLOAD16(gp, lp)                                                     \
    __builtin_amdgcn_global_load_lds(                                       \
        (const __attribute__((address_space(1))) unsigned int*)(gp),        \
        (__attribute__((address_space(3))) unsigned int*)(lp), 16, 0, 0)

// ---- Kernel 1 (prep): gq = bf16(g)^T tiles ; e1 = h·a1 ;
//      e2B = exp(e2), e2D = exp(0.2*e2)  (factorized-softmax tables) ---------
__global__ __launch_bounds__(256) void prep(
    const float* __restrict__ g, const float* __restrict__ h,
    const float* __restrict__ a1, const float* __restrict__ a2,
    ushort_t* __restrict__ gq, float* __restrict__ e1,
    float* __restrict__ e2B, float* __restrict__ e2D)
{
    __shared__ ushort_t tl[DD][66];  // +2 pad breaks write bank conflicts
    int b = blockIdx.y, m0 = blockIdx.x * 64, t = threadIdx.x;

    #pragma unroll
    for (int i = 0; i < 8; i++) {
        int idx = i * 256 + t;
        int m = idx >> 5;            // 32 consecutive lanes share row m
        int c4 = (idx & 31) * 4;
        float4 v = *(const float4*)(h + ((size_t)(b * NN + m0 + m)) * DD + c4);
        float4 av = *(const float4*)(a1 + c4);
        float p = v.x * av.x + v.y * av.y + v.z * av.z + v.w * av.w;
        #pragma unroll
        for (int s = 16; s; s >>= 1) p += __shfl_xor(p, s);
        if ((t & 31) == 0) e1[b * NN + m0 + m] = p;
    }
    #pragma unroll
    for (int i = 0; i < 8; i++) {
        int idx = i * 256 + t;
        int m = idx >> 5;
        int c4 = (idx & 31) * 4;
        float4 v = *(const float4*)(g + ((size_t)(b * MM + m0 + m)) * DD + c4);
        tl[c4 + 0][m] = (ushort_t)f2bf(v.x);
        tl[c4 + 1][m] = (ushort_t)f2bf(v.y);
        tl[c4 + 2][m] = (ushort_t)f2bf(v.z);
        tl[c4 + 3][m] = (ushort_t)f2bf(v.w);
        float4 av = *(const float4*)(a2 + c4);
        float p = v.x * av.x + v.y * av.y + v.z * av.z + v.w * av.w;
        #pragma unroll
        for (int s = 16; s; s >>= 1) p += __shfl_xor(p, s);
        if ((t & 31) == 0) {
            e2B[b * MM + m0 + m] = __builtin_amdgcn_exp2f(L2E * p);
            e2D[b * MM + m0 + m] = __builtin_amdgcn_exp2f(0.2f * L2E * p);
        }
    }
    __syncthreads();
    #pragma unroll
    for (int i = 0; i < 4; i++) {
        int idx = i * 256 + t;
        int d = idx >> 3;            // 0..127
        int c = (idx & 7) * 8;       // local m group
        int4 o;
        o.x = (int)((unsigned)tl[d][c + 0] | ((unsigned)tl[d][c + 1] << 16));
        o.y = (int)((unsigned)tl[d][c + 2] | ((unsigned)tl[d][c + 3] << 16));
        o.z = (int)((unsigned)tl[d][c + 4] | ((unsigned)tl[d][c + 5] << 16));
        o.w = (int)((unsigned)tl[d][c + 6] | ((unsigned)tl[d][c + 7] << 16));
        int mg = m0 + c;
        *(int4*)(gq + (((size_t)((b * 32 + (mg >> 5)) * DD + d)) << 5) + (mg & 31)) = o;
    }
}

// ---- Kernel 2: in-block pack + softmax + PV ---------------------------------
// Phase A: block packs its OWN 64 adj rows (256 KB contiguous, full HBM rate)
// into an 8 KB LDS bitmask + deg. Phase B: r16-style lean loop — gq-only DMA
// dbuf (16 KB/chunk, 16 iterations), mask/tables from LDS, factorized softmax.
// No global mask, no second adj pass. LDS 48 KB -> 2 blocks/CU.
__global__ __launch_bounds__(256, 2) void attn_tiled(
    const int* __restrict__ adj, const ushort_t* __restrict__ gq,
    const float* __restrict__ e1, const float* __restrict__ e2B,
    const float* __restrict__ e2D, float* __restrict__ out)
{
    __shared__ __align__(16) float BfS[MM];                 // 4 KB
    __shared__ __align__(16) float DfS[MM];                 // 4 KB
    __shared__ __align__(16) uint_t maskS[64 * 32];         // 8 KB
    __shared__ float degS[64];
    __shared__ __align__(16) ushort_t gqS[2][2 * 128 * 32]; // 2 x 16 KB

    int b = blockIdx.y, n0 = blockIdx.x * 64, t = threadIdx.x;
    int wid = t >> 6, lane = t & 63;
    int rlo = lane & 15, hh = lane >> 4;
    int r = wid * 16 + rlo;          // block-local row 0..63

    // stage tables
    *(float4*)(&BfS[t * 4]) = *(const float4*)(e2B + b * MM + t * 4);
    *(float4*)(&DfS[t * 4]) = *(const float4*)(e2D + b * MM + t * 4);
    float e1r = e1[b * NN + n0 + r];
    float An   = __builtin_amdgcn_exp2f(L2E * e1r);
    float Cn   = __builtin_amdgcn_exp2f(0.2f * L2E * e1r);
    float invA = __builtin_amdgcn_exp2f(-L2E * e1r);

    const int* adjb = adj + (size_t)(b * NN + n0) * MM;
    const ushort_t* gqb = gq + (size_t)b * (32 * DD * 32);

    // ---- Phase A: pack own rows (wave w packs rows 16w..16w+15) ----
#define PACKROW(ROW, V0, V1, V2, V3) do {                                   \
        int cnt = 0; int sw = 2 * ((ROW) & 15);                             \
        int4 vv[4] = {V0, V1, V2, V3};                                      \
        _Pragma("unroll")                                                   \
        for (int rr = 0; rr < 4; rr++) {                                    \
            uint_t nib = (vv[rr].x > 0 ? 1u:0u) | (vv[rr].y > 0 ? 2u:0u)    \
                       | (vv[rr].z > 0 ? 4u:0u) | (vv[rr].w > 0 ? 8u:0u);   \
            cnt += __popc(nib);                                             \
            uint_t val = nib << (4 * (lane & 7));                           \
            val |= __shfl_xor(val, 1);                                      \
            val |= __shfl_xor(val, 2);                                      \
            val |= __shfl_xor(val, 4);                                      \
            if ((lane & 7) == 0)                                            \
                maskS[(ROW) * 32 + ((rr * 8 + (lane >> 3)) ^ sw)] = val;    \
        }                                                                   \
        _Pragma("unroll")                                                   \
        for (int s = 32; s; s >>= 1) cnt += __shfl_xor(cnt, s);             \
        if (lane == 0) degS[ROW] = (float)cnt;                              \
    } while (0)

    #pragma unroll 1
    for (int i = 0; i < 16; i += 2) {
        int row0 = wid * 16 + i, row1 = row0 + 1;
        const int* ap0 = adjb + (size_t)row0 * MM + lane * 4;
        const int* ap1 = adjb + (size_t)row1 * MM + lane * 4;
        int4 u0 = *(const int4*)(ap0);
        int4 u1 = *(const int4*)(ap0 + 256);
        int4 u2 = *(const int4*)(ap0 + 512);
        int4 u3 = *(const int4*)(ap0 + 768);
        int4 w0 = *(const int4*)(ap1);
        int4 w1 = *(const int4*)(ap1 + 256);
        int4 w2 = *(const int4*)(ap1 + 512);
        int4 w3 = *(const int4*)(ap1 + 768);
        PACKROW(row0, u0, u1, u2, u3);
        PACKROW(row1, w0, w1, w2, w3);
    }
#undef PACKROW
    __syncthreads();                 // mask/deg/tables visible; no DMA yet

    // ---- Phase B: gq-only DMA double-buffer, 16 chunks of 64 m ----
    // gq staging: 1024 slots = 2 m-tiles x (128 d x 4 slots of 8 shorts),
    // src-swizzled seg = slot ^ ((d>>1)&3)
    int gtile[4], goff[4];
    #pragma unroll
    for (int i = 0; i < 4; i++) {
        int di = t + i * 256;
        gtile[i] = di >> 9;
        int idx = di & 511;
        int gd = idx >> 2, gseg = (idx & 3) ^ ((gd >> 1) & 3);
        goff[i] = gd * 32 + gseg * 8;
    }

#define STAGE(P, K) do {                                                    \
        _Pragma("unroll")                                                   \
        for (int i = 0; i < 4; i++)                                         \
            GLOAD16(gqb + (size_t)(2 * (K) + gtile[i]) * 4096 + goff[i],    \
                    &gqS[P][(t + i * 256) * 8]);                            \
    } while (0)

    f32x4 acc[8];
    #pragma unroll
    for (int j = 0; j < 8; j++) acc[j] = (f32x4){0.f, 0.f, 0.f, 0.f};
    float zl = 0.f;

#define KSTEP(P, K, KS) do {                                                \
        uint_t mw = maskS[r * 32 + ((2 * (K) + (KS)) ^ (2 * rlo))];         \
        uint_t mby = (mw >> (8 * hh)) & 0xffu;                              \
        int mo = (K) * 64 + (KS) * 32 + 8 * hh;                             \
        float4 b0 = *(const float4*)(&BfS[mo]);                             \
        float4 b1 = *(const float4*)(&BfS[mo + 4]);                         \
        float4 d0 = *(const float4*)(&DfS[mo]);                             \
        float4 d1 = *(const float4*)(&DfS[mo + 4]);                         \
        float Bv[8] = {b0.x, b0.y, b0.z, b0.w, b1.x, b1.y, b1.z, b1.w};     \
        float Dv[8] = {d0.x, d0.y, d0.z, d0.w, d1.x, d1.y, d1.z, d1.w};     \
        bf16x8 af;                                                          \
        _Pragma("unroll")                                                   \
        for (int jj = 0; jj < 8; jj++) {                                    \
            float val = (Bv[jj] > invA) ? Bv[jj] * An : Dv[jj] * Cn;        \
            float wv = ((mby >> jj) & 1u) ? val : 0.f;                      \
            zl += wv;                                                       \
            af[jj] = (__bf16)wv;                                            \
        }                                                                   \
        _Pragma("unroll")                                                   \
        for (int j = 0; j < 8; j++) {                                       \
            int d = j * 16 + rlo;                                           \
            int4 bv = *(const int4*)(&gqS[P][(KS) * 4096 + d * 32 +         \
                                             (hh ^ ((rlo >> 1) & 3)) * 8]); \
            acc[j] = __builtin_amdgcn_mfma_f32_16x16x32_bf16(               \
                         af, __builtin_bit_cast(bf16x8, bv), acc[j], 0,0,0);\
        }                                                                   \
    } while (0)

    STAGE(0, 0);

    for (int k = 0; k < 16; ++k) {
        asm volatile("s_waitcnt vmcnt(0)" ::: "memory");  // stage k landed
        __builtin_amdgcn_s_barrier();                     // raw: no drain
        __builtin_amdgcn_sched_barrier(0);
        if (k < 15) STAGE((k + 1) & 1, k + 1);
        KSTEP(k & 1, k, 0);
        KSTEP(k & 1, k, 1);
    }

#undef KSTEP
#undef STAGE

    // per-row Z: lanes sharing rlo hold partials -> reduce lane bits 4,5
    zl += __shfl_xor(zl, 16); zl += __shfl_xor(zl, 32);
    float dgv = degS[r];
    float sc = (dgv > 0.f) ? (dgv / zl) : 0.f;           // = deg / Z

    float scr[4];
    #pragma unroll
    for (int rg = 0; rg < 4; rg++) scr[rg] = __shfl(sc, 4 * hh + rg);

    // C layout: col = rlo, row(within frag) = 4*hh + rg
    float* ob = out + ((size_t)(b * NN + n0 + wid * 16)) * DD + rlo;
    #pragma unroll
    for (int j = 0; j < 8; j++)
        #pragma unroll
        for (int rg = 0; rg < 4; rg++)
            ob[(size_t)(4 * hh + rg) * DD + j * 16] = acc[j][rg] * scr[rg];
}

extern "C" void kernel_launch(void* const* d_in, const int* in_sizes, int n_in,
                              void* d_out, int out_size, void* d_ws, size_t ws_size,
                              hipStream_t stream) {
    const float* h   = (const float*)d_in[0];
    const float* g   = (const float*)d_in[1];
    const int*   adj = (const int*)d_in[2];
    const float* a1  = (const float*)d_in[3];
    const float* a2  = (const float*)d_in[4];
    float* out = (float*)d_out;

    // workspace: e1 @0 (128 KB), e2B @128K (128 KB), e2D @256K (128 KB),
    //            gq @512K (8 MB)
    char* ws = (char*)d_ws;
    float*    e1  = (float*)(ws);
    float*    e2B = (float*)(ws + (128u << 10));
    float*    e2D = (float*)(ws + (256u << 10));
    ushort_t* gq  = (ushort_t*)(ws + (512u << 10));

    prep<<<dim3(MM / 64, BB), 256, 0, stream>>>(g, h, a1, a2, gq, e1, e2B, e2D);
    attn_tiled<<<dim3(NN / 64, BB), 256, 0, stream>>>(adj, gq, e1, e2B, e2D, out);
}